// Round 1
// baseline (1355.680 us; speedup 1.0000x reference)
//
#include <hip/hip_runtime.h>
#include <stdint.h>

#define B      256
#define DIN    700
#define T      250
#define H      1024
#define DOUT   20
#define NW_IN  11     // u64 words for 700 input bits
#define NW_INP 12     // padded
#define NW_H   16     // u64 words for 1024 hidden bits

typedef unsigned long long u64;

// ---------------- prep: transpose weights ----------------
__global__ void prep_weights(const float* __restrict__ W_hid,
                             const float* __restrict__ W_out,
                             float* __restrict__ Wt,
                             float* __restrict__ WoT) {
    int idx = blockIdx.x * 256 + threadIdx.x;
    if (blockIdx.x < 2800) {
        int d = idx / H;
        int h = idx - d * H;
        Wt[idx] = W_hid[h * DIN + d];
    } else {
        int i = idx - 2800 * 256;   // 0..20479
        int h = i / DOUT;
        int o = i - h * DOUT;
        WoT[i] = W_out[o * H + h];
    }
}

// ---------------- prep: bitpack spikes ----------------
__global__ void prep_bits(const float* __restrict__ spk,
                          u64* __restrict__ bits) {
    int b  = blockIdx.x >> 2;
    int wc = blockIdx.x & 3;
    int t  = threadIdx.x;
    if (t >= T) return;
    int w0 = wc * 3;
    int w1 = (wc == 3) ? NW_IN : w0 + 3;
    const float* base = spk + (size_t)b * DIN * T + t;
    for (int w = w0; w < w1; ++w) {
        u64 m = 0;
#pragma unroll
        for (int j = 0; j < 64; ++j) {
            int d = (w << 6) + j;
            if (d < DIN) {
                float x = base[(size_t)d * T];
                m |= (u64)(x > 0.5f) << j;
            }
        }
        bits[((size_t)b * T + t) * NW_INP + w] = m;
    }
}

// ---------------- hidden layer: float4-per-thread gather + scan ----------------
// 256 threads/block, thread owns h = 4*tid .. 4*tid+3 (4 consecutive h).
// Per active input j: 1 amortized ds_read_b128 (4 idx), 1 v_add_u32,
// 1 global_load_dwordx4, 4 v_add_f32  -> ~3.4x fewer issue-ops per useful
// add than the 16-wave scalar version. Per-h summation order is UNCHANGED
// (sequential fp32, ascending d), so the result stays bit-exact.
// Spike bits are re-permuted via nibble+shfl so hsbits keeps the PLAIN
// layout (bit l of word w == h = 64*w + l) -> downstream kernels unchanged.
#define GLD(off) (*(const float4*)(wbase + (off)))
#define ACC(v)   { a0 += (v).x; a1 += (v).y; a2 += (v).z; a3 += (v).w; }

__global__ void __launch_bounds__(256)
hidden_kernel(const u64* __restrict__ bits,
              const float* __restrict__ Wt,
              const float* __restrict__ hs0,
              const float* __restrict__ hv0,
              u64* __restrict__ hsbits) {
    __shared__ alignas(16) int idx_l[2][256];

    int b    = blockIdx.x;
    int tid  = threadIdx.x;
    int wv   = tid >> 6;
    int lane = tid & 63;
    int h0   = tid << 2;

    float4 kv = *(const float4*)(hv0 + (size_t)b * H + h0);
    float4 ks = *(const float4*)(hs0 + (size_t)b * H + h0);
    float k0 = kv.x * 0.5f * (1.0f - ks.x);
    float k1 = kv.y * 0.5f * (1.0f - ks.y);
    float k2 = kv.z * 0.5f * (1.0f - ks.z);
    float k3 = kv.w * 0.5f * (1.0f - ks.w);

    const u64*  bb    = bits + (size_t)b * T * NW_INP;
    const char* wbase = (const char*)Wt + (tid << 4);   // thread's column base
    u64*        hrow  = hsbits + (size_t)b * T * NW_H;

    u64 wc[NW_IN];
#pragma unroll
    for (int k = 0; k < NW_IN; ++k) wc[k] = bb[k];

    for (int t = 0; t < T; ++t) {
        // prefix bases (redundant per thread; scalar-unit friendly)
        int base[NW_IN + 1];
        base[0] = 0;
#pragma unroll
        for (int k = 0; k < NW_IN; ++k) base[k + 1] = base[k] + __popcll(wc[k]);
        int n = base[NW_IN];

        int buf = t & 1;
        // ordered expansion of active indices (ascending d), as byte offsets j*4096
#pragma unroll
        for (int rep = 0; rep < 3; ++rep) {
            int w = wv + (rep << 2);
            if (w < NW_IN) {
                u64 m = wc[w];
                if ((m >> lane) & 1ull) {
                    int pos = base[w] + __popcll(m & ((1ull << lane) - 1ull));
                    idx_l[buf][pos] = ((w << 6) + lane) << 12;
                }
            }
        }

        // prefetch next-t bit words while this t is processed
        u64 wn[NW_IN];
        if (t + 1 < T) {
            const u64* np = bb + (size_t)(t + 1) * NW_INP;
#pragma unroll
            for (int k = 0; k < NW_IN; ++k) wn[k] = np[k];
        } else {
#pragma unroll
            for (int k = 0; k < NW_IN; ++k) wn[k] = 0;
        }

        __syncthreads();

        const int* il = idx_l[buf];
        float a0 = 0.0f, a1 = 0.0f, a2 = 0.0f, a3 = 0.0f;
        int n16 = n & ~15;
        int i = 0;
        // 16-wide software pipeline: second group of 8 loads + index reads
        // are issued before the first group's adds consume (vmcnt>0 overlap)
        for (; i < n16; i += 16) {
            int4 ia = *(const int4*)(il + i);
            int4 ib = *(const int4*)(il + i + 4);
            float4 v0 = GLD(ia.x), v1 = GLD(ia.y), v2 = GLD(ia.z), v3 = GLD(ia.w);
            float4 v4 = GLD(ib.x), v5 = GLD(ib.y), v6 = GLD(ib.z), v7 = GLD(ib.w);
            int4 ic = *(const int4*)(il + i + 8);
            int4 id = *(const int4*)(il + i + 12);
            float4 u0 = GLD(ic.x), u1 = GLD(ic.y), u2 = GLD(ic.z), u3 = GLD(ic.w);
            float4 u4 = GLD(id.x), u5 = GLD(id.y), u6 = GLD(id.z), u7 = GLD(id.w);
            ACC(v0) ACC(v1) ACC(v2) ACC(v3) ACC(v4) ACC(v5) ACC(v6) ACC(v7)
            ACC(u0) ACC(u1) ACC(u2) ACC(u3) ACC(u4) ACC(u5) ACC(u6) ACC(u7)
        }
        if (n - i >= 8) {
            int4 ia = *(const int4*)(il + i);
            int4 ib = *(const int4*)(il + i + 4);
            float4 v0 = GLD(ia.x), v1 = GLD(ia.y), v2 = GLD(ia.z), v3 = GLD(ia.w);
            float4 v4 = GLD(ib.x), v5 = GLD(ib.y), v6 = GLD(ib.z), v7 = GLD(ib.w);
            ACC(v0) ACC(v1) ACC(v2) ACC(v3) ACC(v4) ACC(v5) ACC(v6) ACC(v7)
            i += 8;
        }
        for (; i < n; ++i) {
            float4 v = GLD(il[i]);
            ACC(v)
        }

        // membrane update + spike (identical arithmetic/order to before)
        float hva = k0 + a0;  int s0 = hva > 0.5f;  k0 = s0 ? 0.0f : hva * 0.5f;
        float hvb = k1 + a1;  int s1 = hvb > 0.5f;  k1 = s1 ? 0.0f : hvb * 0.5f;
        float hvc = k2 + a2;  int s2 = hvc > 0.5f;  k2 = s2 ? 0.0f : hvc * 0.5f;
        float hvd = k3 + a3;  int s3 = hvd > 0.5f;  k3 = s3 ? 0.0f : hvd * 0.5f;

        // plain-layout ballot: word (4*wv+k) bit l  <-  h = 256*wv + 64*k + l
        // = thread (16*k + (l>>2)) of this wave, nibble bit (l&3)
        int nib = s0 | (s1 << 1) | (s2 << 2) | (s3 << 3);
        u64* rp = hrow + (size_t)t * NW_H + (wv << 2);
#pragma unroll
        for (int k = 0; k < 4; ++k) {
            int src = (k << 4) + (lane >> 2);
            int v   = __shfl(nib, src, 64);
            int bit = (v >> (lane & 3)) & 1;
            u64 ball = __ballot(bit);
            if (lane == 0) rp[k] = ball;
        }

#pragma unroll
        for (int k = 0; k < NW_IN; ++k) wc[k] = wn[k];
    }
}

// ---------------- output currents: Iout[b*T+t][o] ----------------
__global__ void __launch_bounds__(256)
out_currents(const u64* __restrict__ hsbits,
             const float* __restrict__ WoT,
             float* __restrict__ Iout) {
    __shared__ int lidx[4][2][256];

    int wv   = threadIdx.x >> 6;
    int lane = threadIdx.x & 63;
    int row  = blockIdx.x * 4 + wv;   // < 64000 exactly

    const u64* wp = hsbits + (size_t)row * NW_H;

    float acc = 0.0f;
#pragma unroll
    for (int g = 0; g < 4; ++g) {
        u64 w[4];
#pragma unroll
        for (int k = 0; k < 4; ++k) w[k] = wp[g * 4 + k];

        int base[5];
        base[0] = 0;
#pragma unroll
        for (int k = 0; k < 4; ++k) base[k + 1] = base[k] + __popcll(w[k]);
        int n = base[4];

        int buf = g & 1;
#pragma unroll
        for (int k = 0; k < 4; ++k) {
            u64 m = w[k];
            if ((m >> lane) & 1ull) {
                int pos = base[k] + __popcll(m & ((1ull << lane) - 1ull));
                lidx[wv][buf][pos] = ((g * 4 + k) << 6) + lane;
            }
        }
        __syncthreads();

        const int* il = lidx[wv][buf];
        int i = 0;
        for (; i + 4 <= n; i += 4) {
            int j0 = il[i + 0], j1 = il[i + 1], j2 = il[i + 2], j3 = il[i + 3];
            if (lane < DOUT) {
                float v0 = WoT[(size_t)j0 * DOUT + lane];
                float v1 = WoT[(size_t)j1 * DOUT + lane];
                float v2 = WoT[(size_t)j2 * DOUT + lane];
                float v3 = WoT[(size_t)j3 * DOUT + lane];
                acc += v0; acc += v1; acc += v2; acc += v3;
            }
        }
        for (; i < n; ++i) {
            if (lane < DOUT) acc += WoT[(size_t)il[i] * DOUT + lane];
        }
    }
    if (lane < DOUT) Iout[(size_t)row * DOUT + lane] = acc;
}

// ---------------- output scan + spike count ----------------
__global__ void out_scan(const float* __restrict__ Iout,
                         const float* __restrict__ os0,
                         const float* __restrict__ ov0,
                         float* __restrict__ outp) {
    int idx = blockIdx.x * 256 + threadIdx.x;
    if (idx >= B * DOUT) return;
    int b = idx / DOUT;
    int o = idx - b * DOUT;

    float ov = ov0[idx];
    float os = os0[idx];
    float keep = ov * 0.5f * (1.0f - os);
    float cnt = 0.0f;
    const float* ip = Iout + (size_t)b * T * DOUT + o;
#pragma unroll 5
    for (int t = 0; t < T; ++t) {
        float v = keep + ip[(size_t)t * DOUT];
        float s = (v > 0.5f) ? 1.0f : 0.0f;
        cnt += s;
        keep = v * 0.5f * (1.0f - s);
    }
    outp[idx] = cnt;
}

extern "C" void kernel_launch(void* const* d_in, const int* in_sizes, int n_in,
                              void* d_out, int out_size, void* d_ws, size_t ws_size,
                              hipStream_t stream) {
    const float* spike = (const float*)d_in[0];   // [256][700][250]
    const float* W_hid = (const float*)d_in[1];   // [1024][700]
    const float* W_out = (const float*)d_in[2];   // [20][1024]
    const float* hs0   = (const float*)d_in[3];   // [256][1024]
    const float* hv0   = (const float*)d_in[4];
    const float* os0   = (const float*)d_in[5];   // [256][20]
    const float* ov0   = (const float*)d_in[6];
    float* outp = (float*)d_out;                  // [256][20]

    char* ws = (char*)d_ws;
    float* Wt     = (float*)(ws);                               // 2,867,200 B
    float* WoT    = (float*)(ws + 2867200);                     //    81,920 B
    u64*   bits   = (u64*)  (ws + 2949120);                     // 6,144,000 B
    u64*   hsbits = (u64*)  (ws + 9093120);                     // 8,192,000 B
    float* Iout   = (float*)(ws + 17285120);                    // 5,120,000 B

    prep_weights<<<2880, 256, 0, stream>>>(W_hid, W_out, Wt, WoT);
    prep_bits<<<1024, 256, 0, stream>>>(spike, bits);
    hidden_kernel<<<B, 256, 0, stream>>>(bits, Wt, hs0, hv0, hsbits);
    out_currents<<<16000, 256, 0, stream>>>(hsbits, WoT, Iout);
    out_scan<<<20, 256, 0, stream>>>(Iout, os0, ov0, outp);
}

// Round 2
// 1152.021 us; speedup vs baseline: 1.1768x; 1.1768x over previous
//
#include <hip/hip_runtime.h>
#include <stdint.h>

#define B      256
#define DIN    700
#define T      250
#define H      1024
#define DOUT   20
#define NW_IN  11     // u64 words for 700 input bits
#define NW_INP 12     // padded
#define NW_H   16     // u64 words for 1024 hidden bits

typedef unsigned long long u64;

// ---------------- prep: transpose weights ----------------
__global__ void prep_weights(const float* __restrict__ W_hid,
                             const float* __restrict__ W_out,
                             float* __restrict__ Wt,
                             float* __restrict__ WoT) {
    int idx = blockIdx.x * 256 + threadIdx.x;
    if (blockIdx.x < 2800) {
        int d = idx / H;
        int h = idx - d * H;
        Wt[idx] = W_hid[h * DIN + d];
    } else {
        int i = idx - 2800 * 256;   // 0..20479
        int h = i / DOUT;
        int o = i - h * DOUT;
        WoT[i] = W_out[o * H + h];
    }
}

// ---------------- prep: bitpack spikes ----------------
__global__ void prep_bits(const float* __restrict__ spk,
                          u64* __restrict__ bits) {
    int b  = blockIdx.x >> 2;
    int wc = blockIdx.x & 3;
    int t  = threadIdx.x;
    if (t >= T) return;
    int w0 = wc * 3;
    int w1 = (wc == 3) ? NW_IN : w0 + 3;
    const float* base = spk + (size_t)b * DIN * T + t;
    for (int w = w0; w < w1; ++w) {
        u64 m = 0;
#pragma unroll
        for (int j = 0; j < 64; ++j) {
            int d = (w << 6) + j;
            if (d < DIN) {
                float x = base[(size_t)d * T];
                m |= (u64)(x > 0.5f) << j;
            }
        }
        bits[((size_t)b * T + t) * NW_INP + w] = m;
    }
}

#define GLD(off) (*(const float4*)(wbase + (off)))
#define ACC(v)   { a0 += (v).x; a1 += (v).y; a2 += (v).z; a3 += (v).w; }

// ---------------- hidden currents: parallel over ALL (b,t) rows ----------------
// cur(b,t,h) = sum over active j of Wt[j][h] is independent of hidden state ->
// massively parallel. One block per (b,t) row, 256 threads, float4 over h.
// Per-h summation order identical to the fused kernel (ascending d, sequential
// fp32 in each lane) -> bit-exact. Expected L2-BW-bound (~18 GB from
// L2-resident Wt), latency hidden by ~8 blocks/CU.
__global__ void __launch_bounds__(256)
hid_currents(const u64* __restrict__ bits,
             const float* __restrict__ Wt,
             float* __restrict__ Ihid,
             int t0, int nt) {
    __shared__ alignas(16) int idx_l[256];

    int i    = blockIdx.x;        // within chunk
    int b    = blockIdx.y;
    int t    = t0 + i;
    int tid  = threadIdx.x;
    int wv   = tid >> 6;
    int lane = tid & 63;

    const u64* wp = bits + ((size_t)b * T + t) * NW_INP;
    u64 w[NW_IN];
#pragma unroll
    for (int k = 0; k < NW_IN; ++k) w[k] = wp[k];

    int base[NW_IN + 1];
    base[0] = 0;
#pragma unroll
    for (int k = 0; k < NW_IN; ++k) base[k + 1] = base[k] + __popcll(w[k]);
    int n = base[NW_IN];

    // ordered expansion of active indices (ascending d), as byte offsets j*4096
#pragma unroll
    for (int rep = 0; rep < 3; ++rep) {
        int ww = wv + (rep << 2);
        if (ww < NW_IN) {
            u64 m = w[ww];
            if ((m >> lane) & 1ull) {
                int pos = base[ww] + __popcll(m & ((1ull << lane) - 1ull));
                idx_l[pos] = ((ww << 6) + lane) << 12;
            }
        }
    }
    __syncthreads();

    const char* wbase = (const char*)Wt + (tid << 4);
    const int* il = idx_l;
    float a0 = 0.0f, a1 = 0.0f, a2 = 0.0f, a3 = 0.0f;
    int n16 = n & ~15;
    int i2 = 0;
    for (; i2 < n16; i2 += 16) {
        int4 ia = *(const int4*)(il + i2);
        int4 ib = *(const int4*)(il + i2 + 4);
        float4 v0 = GLD(ia.x), v1 = GLD(ia.y), v2 = GLD(ia.z), v3 = GLD(ia.w);
        float4 v4 = GLD(ib.x), v5 = GLD(ib.y), v6 = GLD(ib.z), v7 = GLD(ib.w);
        int4 ic = *(const int4*)(il + i2 + 8);
        int4 id = *(const int4*)(il + i2 + 12);
        float4 u0 = GLD(ic.x), u1 = GLD(ic.y), u2 = GLD(ic.z), u3 = GLD(ic.w);
        float4 u4 = GLD(id.x), u5 = GLD(id.y), u6 = GLD(id.z), u7 = GLD(id.w);
        ACC(v0) ACC(v1) ACC(v2) ACC(v3) ACC(v4) ACC(v5) ACC(v6) ACC(v7)
        ACC(u0) ACC(u1) ACC(u2) ACC(u3) ACC(u4) ACC(u5) ACC(u6) ACC(u7)
    }
    if (n - i2 >= 8) {
        int4 ia = *(const int4*)(il + i2);
        int4 ib = *(const int4*)(il + i2 + 4);
        float4 v0 = GLD(ia.x), v1 = GLD(ia.y), v2 = GLD(ia.z), v3 = GLD(ia.w);
        float4 v4 = GLD(ib.x), v5 = GLD(ib.y), v6 = GLD(ib.z), v7 = GLD(ib.w);
        ACC(v0) ACC(v1) ACC(v2) ACC(v3) ACC(v4) ACC(v5) ACC(v6) ACC(v7)
        i2 += 8;
    }
    for (; i2 < n; ++i2) {
        float4 v = GLD(il[i2]);
        ACC(v)
    }

    float4 o; o.x = a0; o.y = a1; o.z = a2; o.w = a3;
    *(float4*)(Ihid + ((size_t)b * nt + i) * H + (tid << 2)) = o;
}

// ---------------- hidden scan: cheap serial recurrence over t ----------------
// 256 blocks x 1024 threads (scalar h). Identical arithmetic & ballot layout
// to the original fused kernel.
__global__ void __launch_bounds__(1024)
hid_scan(const float* __restrict__ Ihid,
         const float* __restrict__ hs0,
         const float* __restrict__ hv0,
         float* __restrict__ keepbuf,
         u64* __restrict__ hsbits,
         int t0, int nt) {
    int b    = blockIdx.x;
    int h    = threadIdx.x;
    int wv   = h >> 6;
    int lane = h & 63;

    float keep;
    if (t0 == 0)
        keep = hv0[b * H + h] * 0.5f * (1.0f - hs0[b * H + h]);
    else
        keep = keepbuf[b * H + h];

    const float* ip = Ihid + (size_t)b * nt * H + h;
    float cur = ip[0];
    for (int i = 0; i < nt; ++i) {
        float nxt = (i + 1 < nt) ? ip[(size_t)(i + 1) * H] : 0.0f;
        float hv = keep + cur;
        bool s = hv > 0.5f;
        keep = s ? 0.0f : hv * 0.5f;
        u64 ball = __ballot(s);
        if (lane == 0)
            hsbits[((size_t)b * T + t0 + i) * NW_H + wv] = ball;
        cur = nxt;
    }
    if (t0 + nt < T)
        keepbuf[b * H + h] = keep;
}

// ---------------- fallback: round-0 fused hidden kernel (proven) ----------------
__global__ void __launch_bounds__(1024)
hidden_fused(const u64* __restrict__ bits,
             const float* __restrict__ Wt,
             const float* __restrict__ hs0,
             const float* __restrict__ hv0,
             u64* __restrict__ hsbits) {
    __shared__ int idx_l[2][256];

    int b = blockIdx.x;
    int h = threadIdx.x;
    int wv   = h >> 6;
    int lane = h & 63;

    float keep = hv0[b * H + h] * 0.5f * (1.0f - hs0[b * H + h]);

    const u64* bb = bits + (size_t)b * T * NW_INP;

    for (int t = 0; t < T; ++t) {
        const u64* wp = bb + (size_t)t * NW_INP;
        u64 w[NW_IN];
#pragma unroll
        for (int k = 0; k < NW_IN; ++k) w[k] = wp[k];

        int base[NW_IN + 1];
        base[0] = 0;
#pragma unroll
        for (int k = 0; k < NW_IN; ++k) base[k + 1] = base[k] + __popcll(w[k]);
        int n = base[NW_IN];

        int buf = t & 1;
        if (wv < NW_IN) {
            u64 m = w[wv];
            if ((m >> lane) & 1ull) {
                int pos = base[wv] + __popcll(m & ((1ull << lane) - 1ull));
                idx_l[buf][pos] = (wv << 6) + lane;
            }
        }
        __syncthreads();

        const int* il = idx_l[buf];
        float cur = 0.0f;
        int i = 0;
        for (; i + 8 <= n; i += 8) {
            int j0 = il[i + 0], j1 = il[i + 1], j2 = il[i + 2], j3 = il[i + 3];
            int j4 = il[i + 4], j5 = il[i + 5], j6 = il[i + 6], j7 = il[i + 7];
            float v0 = Wt[(size_t)j0 * H + h];
            float v1 = Wt[(size_t)j1 * H + h];
            float v2 = Wt[(size_t)j2 * H + h];
            float v3 = Wt[(size_t)j3 * H + h];
            float v4 = Wt[(size_t)j4 * H + h];
            float v5 = Wt[(size_t)j5 * H + h];
            float v6 = Wt[(size_t)j6 * H + h];
            float v7 = Wt[(size_t)j7 * H + h];
            cur += v0; cur += v1; cur += v2; cur += v3;
            cur += v4; cur += v5; cur += v6; cur += v7;
        }
        for (; i < n; ++i) cur += Wt[(size_t)il[i] * H + h];

        float hv = keep + cur;
        bool s = hv > 0.5f;
        keep = s ? 0.0f : hv * 0.5f;
        u64 ball = __ballot(s);
        if (lane == 0)
            hsbits[((size_t)b * T + t) * NW_H + wv] = ball;
    }
}

// ---------------- output currents: Iout[b*T+t][o] ----------------
__global__ void __launch_bounds__(256)
out_currents(const u64* __restrict__ hsbits,
             const float* __restrict__ WoT,
             float* __restrict__ Iout) {
    __shared__ int lidx[4][2][256];

    int wv   = threadIdx.x >> 6;
    int lane = threadIdx.x & 63;
    int row  = blockIdx.x * 4 + wv;   // < 64000 exactly

    const u64* wp = hsbits + (size_t)row * NW_H;

    float acc = 0.0f;
#pragma unroll
    for (int g = 0; g < 4; ++g) {
        u64 w[4];
#pragma unroll
        for (int k = 0; k < 4; ++k) w[k] = wp[g * 4 + k];

        int base[5];
        base[0] = 0;
#pragma unroll
        for (int k = 0; k < 4; ++k) base[k + 1] = base[k] + __popcll(w[k]);
        int n = base[4];

        int buf = g & 1;
#pragma unroll
        for (int k = 0; k < 4; ++k) {
            u64 m = w[k];
            if ((m >> lane) & 1ull) {
                int pos = base[k] + __popcll(m & ((1ull << lane) - 1ull));
                lidx[wv][buf][pos] = ((g * 4 + k) << 6) + lane;
            }
        }
        __syncthreads();

        const int* il = lidx[wv][buf];
        int i = 0;
        for (; i + 4 <= n; i += 4) {
            int j0 = il[i + 0], j1 = il[i + 1], j2 = il[i + 2], j3 = il[i + 3];
            if (lane < DOUT) {
                float v0 = WoT[(size_t)j0 * DOUT + lane];
                float v1 = WoT[(size_t)j1 * DOUT + lane];
                float v2 = WoT[(size_t)j2 * DOUT + lane];
                float v3 = WoT[(size_t)j3 * DOUT + lane];
                acc += v0; acc += v1; acc += v2; acc += v3;
            }
        }
        for (; i < n; ++i) {
            if (lane < DOUT) acc += WoT[(size_t)il[i] * DOUT + lane];
        }
    }
    if (lane < DOUT) Iout[(size_t)row * DOUT + lane] = acc;
}

// ---------------- output scan + spike count ----------------
__global__ void out_scan(const float* __restrict__ Iout,
                         const float* __restrict__ os0,
                         const float* __restrict__ ov0,
                         float* __restrict__ outp) {
    int idx = blockIdx.x * 256 + threadIdx.x;
    if (idx >= B * DOUT) return;
    int b = idx / DOUT;
    int o = idx - b * DOUT;

    float ov = ov0[idx];
    float os = os0[idx];
    float keep = ov * 0.5f * (1.0f - os);
    float cnt = 0.0f;
    const float* ip = Iout + (size_t)b * T * DOUT + o;
#pragma unroll 5
    for (int t = 0; t < T; ++t) {
        float v = keep + ip[(size_t)t * DOUT];
        float s = (v > 0.5f) ? 1.0f : 0.0f;
        cnt += s;
        keep = v * 0.5f * (1.0f - s);
    }
    outp[idx] = cnt;
}

extern "C" void kernel_launch(void* const* d_in, const int* in_sizes, int n_in,
                              void* d_out, int out_size, void* d_ws, size_t ws_size,
                              hipStream_t stream) {
    const float* spike = (const float*)d_in[0];   // [256][700][250]
    const float* W_hid = (const float*)d_in[1];   // [1024][700]
    const float* W_out = (const float*)d_in[2];   // [20][1024]
    const float* hs0   = (const float*)d_in[3];   // [256][1024]
    const float* hv0   = (const float*)d_in[4];
    const float* os0   = (const float*)d_in[5];   // [256][20]
    const float* ov0   = (const float*)d_in[6];
    float* outp = (float*)d_out;                  // [256][20]

    char* ws = (char*)d_ws;
    float* Wt      = (float*)(ws);                              // 2,867,200 B
    float* WoT     = (float*)(ws + 2867200);                    //    81,920 B
    u64*   bits    = (u64*)  (ws + 2949120);                    // 6,144,000 B
    u64*   hsbits  = (u64*)  (ws + 9093120);                    // 8,192,000 B
    float* Iout    = (float*)(ws + 17285120);                   // 5,120,000 B
    float* keepbuf = (float*)(ws + 22405120);                   // 1,048,576 B
    float* Ihid    = (float*)(ws + 23453696);                   // per-t 1 MiB

    const size_t fixed = 23453696;
    const size_t perT  = (size_t)B * H * 4;      // 1,048,576
    int TC = 0;
    if (ws_size > fixed + perT) {
        size_t avail = (ws_size - fixed) / perT;
        TC = (avail >= T) ? T : (int)avail;
    }

    prep_weights<<<2880, 256, 0, stream>>>(W_hid, W_out, Wt, WoT);
    prep_bits<<<1024, 256, 0, stream>>>(spike, bits);

    if (TC >= 16) {
        for (int t0 = 0; t0 < T; t0 += TC) {
            int nt = (T - t0 < TC) ? (T - t0) : TC;
            hid_currents<<<dim3(nt, B), 256, 0, stream>>>(bits, Wt, Ihid, t0, nt);
            hid_scan<<<B, 1024, 0, stream>>>(Ihid, hs0, hv0, keepbuf, hsbits, t0, nt);
        }
    } else {
        hidden_fused<<<B, 1024, 0, stream>>>(bits, Wt, hs0, hv0, hsbits);
    }

    out_currents<<<16000, 256, 0, stream>>>(hsbits, WoT, Iout);
    out_scan<<<20, 256, 0, stream>>>(Iout, os0, ov0, outp);
}